// Round 10
// baseline (405.647 us; speedup 1.0000x reference)
//
#include <hip/hip_runtime.h>

#define N_USERS 100000
#define N_ITEMS 50000
#define N_NODES 150000
#define N_EDGES 2400000
#define EMB 64
#define LEAKY 0.3f

#define RB_SHIFT 8                                         // 256 rows / bucket
#define RB (1 << RB_SHIFT)
#define NBKT ((N_NODES + RB - 1) >> RB_SHIFT)              // 586
#define SCAN_ITEMS ((NBKT + 255) / 256)                    // 3

#define H_CHUNK 8192
#define NBLK_H ((N_EDGES + H_CHUNK - 1) / H_CHUNK)         // 293
#define L1_CHUNK 2048
#define NBLK_L1 ((N_EDGES + L1_CHUNK - 1) / L1_CHUNK)      // 1172
#define NXCD 8

#define COL_MASK 0x3FFFFu                                  // col < 2^18

typedef unsigned short u16;
typedef unsigned int   u32;

__device__ __forceinline__ u16 f32_to_bf16_rne(float f) {
    u32 u = __float_as_uint(f);
    u32 r = (u + 0x7FFFu + ((u >> 16) & 1u)) >> 16;
    return (u16)r;
}
__device__ __forceinline__ float bf16_lo(u32 x) { return __uint_as_float(x << 16); }
__device__ __forceinline__ float bf16_hi(u32 x) { return __uint_as_float(x & 0xFFFF0000u); }

// bijective XCD swizzle (m204): consecutive logical chunks -> same XCD
__device__ __forceinline__ int xcd_chunk(int bid, int nwg) {
    const int q = nwg / NXCD, r = nwg % NXCD;
    const int xcd = bid & (NXCD - 1), idx = bid >> 3;
    return (xcd < r) ? xcd * (q + 1) + idx
                     : r * (q + 1) + (xcd - r) * q + idx;
}

// ===========================================================================
// e0 -> bf16 (concatenated user ++ item), RNE
// ===========================================================================
__global__ __launch_bounds__(256) void conv_e0(
    const float* __restrict__ uemb, const float* __restrict__ iemb,
    u16* __restrict__ ebf)
{
    const int i = (blockIdx.x * 256 + threadIdx.x) * 4;
    if (i >= N_NODES * EMB) return;
    const float* src = (i < N_USERS * EMB) ? uemb + i : iemb + (i - N_USERS * EMB);
    const float4 v = *(const float4*)src;
    ushort4 w;
    w.x = f32_to_bf16_rne(v.x);
    w.y = f32_to_bf16_rne(v.y);
    w.z = f32_to_bf16_rne(v.z);
    w.w = f32_to_bf16_rne(v.w);
    *(ushort4*)(ebf + i) = w;
}

// ===========================================================================
// Bucket histogram (LDS-aggregated, 586 counters)
// ===========================================================================
__global__ __launch_bounds__(256) void bkt_hist(
    const int* __restrict__ rows, int* __restrict__ gcnt)
{
    __shared__ int cnt[NBKT];
    const int t = threadIdx.x;
    for (int b = t; b < NBKT; b += 256) cnt[b] = 0;
    __syncthreads();

    const int e0 = blockIdx.x * H_CHUNK;
    const int e1 = (e0 + H_CHUNK < N_EDGES) ? e0 + H_CHUNK : N_EDGES;
    for (int i = e0 + t; i < e1; i += 256)
        atomicAdd(&cnt[rows[i] >> RB_SHIFT], 1);
    __syncthreads();

    for (int b = t; b < NBKT; b += 256)
        if (cnt[b]) atomicAdd(&gcnt[b], cnt[b]);
}

// ===========================================================================
// Exclusive scan of the NBKT bucket counts (single block)
// ===========================================================================
__global__ __launch_bounds__(256) void scan_bkt(
    const int* __restrict__ gcnt, int* __restrict__ bkt_ptr,
    int* __restrict__ bkt_tail)
{
    __shared__ int lds[256];
    const int t = threadIdx.x;
    int v[SCAN_ITEMS];
    int s = 0;
    #pragma unroll
    for (int j = 0; j < SCAN_ITEMS; ++j) {
        const int idx = t * SCAN_ITEMS + j;
        v[j] = (idx < NBKT) ? gcnt[idx] : 0;
        s += v[j];
    }
    lds[t] = s;
    __syncthreads();
    for (int off = 1; off < 256; off <<= 1) {
        int x = 0;
        if (t >= off) x = lds[t - off];
        __syncthreads();
        lds[t] += x;
        __syncthreads();
    }
    int run = lds[t] - s;   // exclusive prefix
    #pragma unroll
    for (int j = 0; j < SCAN_ITEMS; ++j) {
        const int idx = t * SCAN_ITEMS + j;
        if (idx < NBKT) {
            bkt_ptr[idx]  = run;
            bkt_tail[idx] = run;
            run += v[j];
        }
    }
    if (t == 255) bkt_ptr[NBKT] = N_EDGES;
}

// ===========================================================================
// Partition: bin edges into 256-row buckets; record = (val, (localrow<<18)|col)
// 1172 blocks; XCD-swizzled so consecutive chunks share an XCD L2 and their
// partial-line appends to the same bucket region merge before eviction.
// ===========================================================================
__global__ __launch_bounds__(256) void partition_l1(
    const float* __restrict__ vals, const int* __restrict__ rows,
    const int* __restrict__ cols, int* __restrict__ bkt_tail,
    float2* __restrict__ svc)
{
    __shared__ int cnt[NBKT];
    __shared__ int base[NBKT];
    const int t = threadIdx.x;
    const int chunk = xcd_chunk(blockIdx.x, NBLK_L1);
    const int e0 = chunk * L1_CHUNK;
    const int e1 = (e0 + L1_CHUNK < N_EDGES) ? e0 + L1_CHUNK : N_EDGES;

    for (int b = t; b < NBKT; b += 256) cnt[b] = 0;
    __syncthreads();

    for (int i = e0 + t; i < e1; i += 256)
        atomicAdd(&cnt[rows[i] >> RB_SHIFT], 1);
    __syncthreads();

    for (int b = t; b < NBKT; b += 256) {
        const int c = cnt[b];
        base[b] = c ? atomicAdd(&bkt_tail[b], c) : 0;
        cnt[b] = 0;
    }
    __syncthreads();

    for (int i = e0 + t; i < e1; i += 256) {
        const int r = rows[i];
        const int b = r >> RB_SHIFT;
        const int pos = base[b] + atomicAdd(&cnt[b], 1);
        const u32 packed = ((u32)(r & (RB - 1)) << 18) | (u32)cols[i];
        svc[pos] = make_float2(vals[i], __uint_as_float(packed));
    }
}

// ===========================================================================
// place_l2 (merged): per-row count (LDS) -> LDS scan -> row_ptr write ->
// in-bucket placement via LDS heads. (round-9 proven)
// ===========================================================================
__global__ __launch_bounds__(256) void place_l2(
    const int* __restrict__ bkt_ptr, const float2* __restrict__ svc,
    float2* __restrict__ sedge, int* __restrict__ row_ptr)
{
    __shared__ int cnt[RB];     // reused as scan array
    __shared__ int heads[RB];
    const int b     = blockIdx.x;
    const int rbase = b << RB_SHIFT;
    const int t     = threadIdx.x;

    cnt[t] = 0;
    __syncthreads();

    const int lo = bkt_ptr[b];
    const int hi = bkt_ptr[b + 1];

    // phase A: per-local-row counts
    for (int i = lo + t; i < hi; i += 256)
        atomicAdd(&cnt[__float_as_uint(svc[i].y) >> 18], 1);
    __syncthreads();

    // phase B: exclusive scan over the 256 counters
    const int v = cnt[t];
    for (int off = 1; off < 256; off <<= 1) {
        int x = 0;
        if (t >= off) x = cnt[t - off];
        __syncthreads();
        cnt[t] += x;
        __syncthreads();
    }
    const int excl = cnt[t] - v;
    heads[t] = lo + excl;
    // row_ptr: every global row once; last bucket's t==240 writes the sentinel
    const int gr = rbase + t;
    if (gr <= N_NODES) row_ptr[gr] = lo + excl;
    __syncthreads();

    // phase C: place edges (writes confined to one ~32KB range -> L2-local)
    for (int i = lo + t; i < hi; i += 256) {
        const float2 vc = svc[i];
        const int lr  = (int)(__float_as_uint(vc.y) >> 18);
        const int pos = atomicAdd(&heads[lr], 1);
        sedge[pos] = vc;
    }
}

// ===========================================================================
// Pull-SpMM over bf16 source: one 64-lane wave per row; lane = (edge-half,
// feature-pair). 8 edges in flight per iteration. (round-8 proven)
// ===========================================================================
__global__ __launch_bounds__(256) void spmm_bf16(
    const int* __restrict__ row_ptr,     // N_NODES+1
    const float2* __restrict__ sedge,    // (val, packed) row-sorted
    const u16* __restrict__ ebf,         // [N_NODES][64] bf16
    float* __restrict__ t_out)           // [N_NODES][64] f32
{
    const int tid  = threadIdx.x;
    const int lane = tid & 63;
    const int row  = blockIdx.x * 4 + (tid >> 6);
    if (row >= N_NODES) return;

    const int h = lane >> 5;    // edge half: 0 or 1
    const int q = lane & 31;    // feature pair: features 2q, 2q+1

    const int beg = row_ptr[row];
    const int end = row_ptr[row + 1];

    float a0 = 0.f, a1 = 0.f, b0 = 0.f, b1 = 0.f;
    float c0 = 0.f, c1 = 0.f, d0 = 0.f, d1 = 0.f;

    int k = beg;
    for (; k + 8 <= end; k += 8) {
        const float2 m0 = sedge[k + 0 + h];
        const float2 m1 = sedge[k + 2 + h];
        const float2 m2 = sedge[k + 4 + h];
        const float2 m3 = sedge[k + 6 + h];
        const u32 i0 = __float_as_uint(m0.y) & COL_MASK;
        const u32 i1 = __float_as_uint(m1.y) & COL_MASK;
        const u32 i2 = __float_as_uint(m2.y) & COL_MASK;
        const u32 i3 = __float_as_uint(m3.y) & COL_MASK;
        const u32 x0 = *((const u32*)(ebf + (size_t)i0 * EMB) + q);
        const u32 x1 = *((const u32*)(ebf + (size_t)i1 * EMB) + q);
        const u32 x2 = *((const u32*)(ebf + (size_t)i2 * EMB) + q);
        const u32 x3 = *((const u32*)(ebf + (size_t)i3 * EMB) + q);
        a0 = fmaf(m0.x, bf16_lo(x0), a0);
        a1 = fmaf(m0.x, bf16_hi(x0), a1);
        b0 = fmaf(m1.x, bf16_lo(x1), b0);
        b1 = fmaf(m1.x, bf16_hi(x1), b1);
        c0 = fmaf(m2.x, bf16_lo(x2), c0);
        c1 = fmaf(m2.x, bf16_hi(x2), c1);
        d0 = fmaf(m3.x, bf16_lo(x3), d0);
        d1 = fmaf(m3.x, bf16_hi(x3), d1);
    }
    for (; k < end; k += 2) {
        const int  kk = k + h;
        const bool on = kk < end;
        const float2 m = sedge[on ? kk : (end - 1)];
        const float  v = on ? m.x : 0.f;
        const u32 ci = __float_as_uint(m.y) & COL_MASK;
        const u32 x  = *((const u32*)(ebf + (size_t)ci * EMB) + q);
        a0 = fmaf(v, bf16_lo(x), a0);
        a1 = fmaf(v, bf16_hi(x), a1);
    }

    float s0 = (a0 + b0) + (c0 + d0);
    float s1 = (a1 + b1) + (c1 + d1);
    s0 += __shfl_xor(s0, 32);
    s1 += __shfl_xor(s1, 32);

    if (h == 0)
        *(float2*)(t_out + (size_t)row * EMB + 2 * q) = make_float2(s0, s1);
}

// ===========================================================================
// Dense stage: e_out = t @ W^T fused with LeakyReLU + 0.25-mean accumulation.
// FIRST also emits e2 as bf16 (stage-2 gather source). (round-8 proven)
// ===========================================================================
template <bool FIRST>
__global__ __launch_bounds__(256) void dense_stage(
    const float* __restrict__ t, const float* __restrict__ W,
    const float* __restrict__ user_emb, const float* __restrict__ item_emb,
    u16* __restrict__ e2bf, float* __restrict__ out)
{
    __shared__ float wT[64][65];
    __shared__ float trow[16][64];

    const int tid = threadIdx.x;
    for (int k = tid; k < 64 * 64; k += 256) {
        const int i = k >> 6, j = k & 63;
        wT[j][i] = W[k];
    }
    const int row_base = blockIdx.x * 16;
    for (int k = tid; k < 16 * 64; k += 256) {
        const int r = k >> 6, j = k & 63;
        const int row = row_base + r;
        trow[r][j] = (row < N_NODES) ? t[(size_t)row * EMB + j] : 0.f;
    }
    __syncthreads();

    const int i  = tid & 63;
    const int r0 = tid >> 6;

    #pragma unroll
    for (int rr = 0; rr < 4; ++rr) {
        const int r   = r0 * 4 + rr;
        const int row = row_base + r;
        if (row >= N_NODES) continue;

        float acc = 0.f;
        #pragma unroll
        for (int j = 0; j < 64; ++j)
            acc = fmaf(trow[r][j], wT[j][i], acc);

        const size_t idx = (size_t)row * EMB + i;
        if (FIRST) {
            const float e1v = acc;
            const float e2v = (e1v >= 0.f) ? e1v : LEAKY * e1v;
            const float e0v = (row < N_USERS)
                                  ? user_emb[idx]
                                  : item_emb[(size_t)(row - N_USERS) * EMB + i];
            e2bf[idx] = f32_to_bf16_rne(e2v);
            out[idx]  = 0.25f * (e0v + e1v + e2v);
        } else {
            out[idx] += 0.25f * acc;
        }
    }
}

// ===========================================================================
// Fallback (round-1 proven): atomic SpMM + f32 dense, if ws too small.
// ===========================================================================
__global__ __launch_bounds__(256) void spmm_atomic(
    const float* __restrict__ vals, const int* __restrict__ rows,
    const int* __restrict__ cols, const float* __restrict__ src_a,
    const float* __restrict__ src_b, float* __restrict__ dst)
{
    const int tid  = threadIdx.x;
    const int lane = tid & 63;
    const int e    = blockIdx.x * 4 + (tid >> 6);
    if (e >= N_EDGES) return;
    const float v = vals[e];
    const int   c = cols[e];
    const int   r = rows[e];
    const float* src = (src_b != nullptr && c >= N_USERS)
                           ? src_b + (size_t)(c - N_USERS) * EMB
                           : src_a + (size_t)c * EMB;
    unsafeAtomicAdd(&dst[(size_t)r * EMB + lane], v * src[lane]);
}

template <bool FIRST>
__global__ __launch_bounds__(256) void dense_f32(
    const float* __restrict__ t, const float* __restrict__ W,
    const float* __restrict__ user_emb, const float* __restrict__ item_emb,
    float* __restrict__ e2, float* __restrict__ out)
{
    __shared__ float wT[64][65];
    __shared__ float trow[16][64];

    const int tid = threadIdx.x;
    for (int k = tid; k < 64 * 64; k += 256) {
        const int i = k >> 6, j = k & 63;
        wT[j][i] = W[k];
    }
    const int row_base = blockIdx.x * 16;
    for (int k = tid; k < 16 * 64; k += 256) {
        const int r = k >> 6, j = k & 63;
        const int row = row_base + r;
        trow[r][j] = (row < N_NODES) ? t[(size_t)row * EMB + j] : 0.f;
    }
    __syncthreads();

    const int i  = tid & 63;
    const int r0 = tid >> 6;

    #pragma unroll
    for (int rr = 0; rr < 4; ++rr) {
        const int r   = r0 * 4 + rr;
        const int row = row_base + r;
        if (row >= N_NODES) continue;
        float acc = 0.f;
        #pragma unroll
        for (int j = 0; j < 64; ++j)
            acc = fmaf(trow[r][j], wT[j][i], acc);
        const size_t idx = (size_t)row * EMB + i;
        if (FIRST) {
            const float e1v = acc;
            const float e2v = (e1v >= 0.f) ? e1v : LEAKY * e1v;
            const float e0v = (row < N_USERS)
                                  ? user_emb[idx]
                                  : item_emb[(size_t)(row - N_USERS) * EMB + i];
            e2[idx]  = e2v;
            out[idx] = 0.25f * (e0v + e1v + e2v);
        } else {
            out[idx] += 0.25f * acc;
        }
    }
}

// ===========================================================================
extern "C" void kernel_launch(void* const* d_in, const int* in_sizes, int n_in,
                              void* d_out, int out_size, void* d_ws, size_t ws_size,
                              hipStream_t stream)
{
    const float* user_emb = (const float*)d_in[0];
    const float* item_emb = (const float*)d_in[1];
    const float* W0       = (const float*)d_in[2];
    const float* W1       = (const float*)d_in[3];
    const float* adj_vals = (const float*)d_in[4];
    const int*   adj_rows = (const int*)d_in[5];
    const int*   adj_cols = (const int*)d_in[6];
    float*       out      = (float*)d_out;

    const size_t mat_bytes = (size_t)N_NODES * EMB * sizeof(float);   // 38.4 MB
    const size_t ebf_bytes = (size_t)N_NODES * EMB * sizeof(u16);     // 19.2 MB
    const size_t edge8     = (size_t)N_EDGES * sizeof(float2);        // 19.2 MB

    // layout: [t 38.4 | svc transient inside t] [sedge 19.2] [ebf 19.2] [aux]
    const size_t off_t      = 0;
    const size_t off_svc    = 0;                       // transient, inside t
    const size_t off_sedge  = off_t + mat_bytes;
    const size_t off_ebf    = off_sedge + edge8;
    const size_t off_rowptr = off_ebf + ebf_bytes;
    const size_t off_gcnt   = off_rowptr + (size_t)(N_NODES + 1) * sizeof(int);
    const size_t off_ptr    = off_gcnt + (size_t)NBKT * sizeof(int);
    const size_t off_tails  = off_ptr + (size_t)(NBKT + 1) * sizeof(int);
    const size_t required   = off_tails + (size_t)NBKT * sizeof(int); // ~77.5 MB

    const int dense_blocks = (N_NODES + 15) / 16;      // 9375
    const int spmm_blocks  = (N_NODES + 3) / 4;        // 37500
    const int conv_blocks  = (N_NODES * EMB / 4 + 255) / 256;

    if (ws_size >= required) {
        float*  t        = (float*)((char*)d_ws + off_t);
        float2* svc      = (float2*)((char*)d_ws + off_svc);
        float2* sedge    = (float2*)((char*)d_ws + off_sedge);
        u16*    ebf      = (u16*)((char*)d_ws + off_ebf);
        int*    row_ptr  = (int*)((char*)d_ws + off_rowptr);
        int*    gcnt     = (int*)((char*)d_ws + off_gcnt);
        int*    bkt_ptr  = (int*)((char*)d_ws + off_ptr);
        int*    bkt_tail = (int*)((char*)d_ws + off_tails);

        // ---- bf16 source for stage 1 ----
        conv_e0<<<conv_blocks, 256, 0, stream>>>(user_emb, item_emb, ebf);

        // ---- bucket-sorted edge list + row_ptr (once, reused twice) ----
        hipMemsetAsync(gcnt, 0, (size_t)NBKT * sizeof(int), stream);
        bkt_hist<<<NBLK_H, 256, 0, stream>>>(adj_rows, gcnt);
        scan_bkt<<<1, 256, 0, stream>>>(gcnt, bkt_ptr, bkt_tail);
        partition_l1<<<NBLK_L1, 256, 0, stream>>>(
            adj_vals, adj_rows, adj_cols, bkt_tail, svc);
        place_l2<<<NBKT, RB, 0, stream>>>(bkt_ptr, svc, sedge, row_ptr);
        // svc (inside t) is dead from here on

        // ---- stage 1: t = A @ e0 ; e1/e2/out ; e2 -> ebf (bf16) ----
        spmm_bf16<<<spmm_blocks, 256, 0, stream>>>(row_ptr, sedge, ebf, t);
        dense_stage<true><<<dense_blocks, 256, 0, stream>>>(
            t, W0, user_emb, item_emb, ebf, out);

        // ---- stage 2: t = A @ e2 ; out += 0.25*e3 ----
        spmm_bf16<<<spmm_blocks, 256, 0, stream>>>(row_ptr, sedge, ebf, t);
        dense_stage<false><<<dense_blocks, 256, 0, stream>>>(
            t, W1, nullptr, nullptr, nullptr, out);
    } else {
        // ---- fallback: round-1 atomic path ----
        float* t  = (float*)d_ws;
        float* e2 = (float*)((char*)d_ws + mat_bytes);

        hipMemsetAsync(t, 0, mat_bytes, stream);
        spmm_atomic<<<(N_EDGES + 3) / 4, 256, 0, stream>>>(
            adj_vals, adj_rows, adj_cols, user_emb, item_emb, t);
        dense_f32<true><<<dense_blocks, 256, 0, stream>>>(
            t, W0, user_emb, item_emb, e2, out);

        hipMemsetAsync(t, 0, mat_bytes, stream);
        spmm_atomic<<<(N_EDGES + 3) / 4, 256, 0, stream>>>(
            adj_vals, adj_rows, adj_cols, e2, nullptr, t);
        dense_f32<false><<<dense_blocks, 256, 0, stream>>>(
            t, W1, nullptr, nullptr, nullptr, out);
    }
}

// Round 11
// 329.950 us; speedup vs baseline: 1.2294x; 1.2294x over previous
//
#include <hip/hip_runtime.h>

#define N_USERS 100000
#define N_ITEMS 50000
#define N_NODES 150000
#define N_EDGES 2400000
#define EMB 64
#define LEAKY 0.3f

#define RB_SHIFT 8                                         // 256 rows / bucket
#define RB (1 << RB_SHIFT)
#define NBKT ((N_NODES + RB - 1) >> RB_SHIFT)              // 586
#define L1_CHUNK 16384
#define NCH ((N_EDGES + L1_CHUNK - 1) / L1_CHUNK)          // 147 chunks
#define COL_MASK 0x3FFFFu                                  // col < 2^18

typedef unsigned short u16;
typedef unsigned int   u32;

__device__ __forceinline__ u16 f32_to_bf16_rne(float f) {
    u32 u = __float_as_uint(f);
    u32 r = (u + 0x7FFFu + ((u >> 16) & 1u)) >> 16;
    return (u16)r;
}
__device__ __forceinline__ float bf16_lo(u32 x) { return __uint_as_float(x << 16); }
__device__ __forceinline__ float bf16_hi(u32 x) { return __uint_as_float(x & 0xFFFF0000u); }

// ===========================================================================
// e0 -> bf16 (concatenated user ++ item), RNE
// ===========================================================================
__global__ __launch_bounds__(256) void conv_e0(
    const float* __restrict__ uemb, const float* __restrict__ iemb,
    u16* __restrict__ ebf)
{
    const int i = (blockIdx.x * 256 + threadIdx.x) * 4;
    if (i >= N_NODES * EMB) return;
    const float* src = (i < N_USERS * EMB) ? uemb + i : iemb + (i - N_USERS * EMB);
    const float4 v = *(const float4*)src;
    ushort4 w;
    w.x = f32_to_bf16_rne(v.x);
    w.y = f32_to_bf16_rne(v.y);
    w.z = f32_to_bf16_rne(v.z);
    w.w = f32_to_bf16_rne(v.w);
    *(ushort4*)(ebf + i) = w;
}

// ===========================================================================
// Per-chunk bucket histogram -> H[chunk][NBKT]  (radix-sort style; no
// global atomics anywhere in the build from here on)
// ===========================================================================
__global__ __launch_bounds__(1024) void bkt_hist(
    const int* __restrict__ rows, int* __restrict__ H)
{
    __shared__ int cnt[NBKT];
    const int t = threadIdx.x;
    const int c = blockIdx.x;
    if (t < NBKT) cnt[t] = 0;
    __syncthreads();

    const int e0 = c * L1_CHUNK;
    const int e1 = (e0 + L1_CHUNK < N_EDGES) ? e0 + L1_CHUNK : N_EDGES;
    for (int i = e0 + t; i < e1; i += 1024)
        atomicAdd(&cnt[rows[i] >> RB_SHIFT], 1);
    __syncthreads();

    if (t < NBKT) H[c * NBKT + t] = cnt[t];
}

// ===========================================================================
// scan_plus (single block, 1024 thr): bucket totals -> exclusive scan ->
// bkt_ptr; then per-(chunk,bucket) bases B[c][b] = bkt_ptr[b] + prefix_c(H).
// Column reads of H are coalesced across threads (thread t = bucket t).
// ===========================================================================
__global__ __launch_bounds__(1024) void scan_plus(
    const int* __restrict__ H, int* __restrict__ bkt_ptr,
    int* __restrict__ B)
{
    __shared__ int lds[1024];
    const int t = threadIdx.x;

    int tot = 0;
    if (t < NBKT) {
        int s0 = 0, s1 = 0, s2 = 0, s3 = 0;
        int c = 0;
        for (; c + 4 <= NCH; c += 4) {
            s0 += H[(c + 0) * NBKT + t];
            s1 += H[(c + 1) * NBKT + t];
            s2 += H[(c + 2) * NBKT + t];
            s3 += H[(c + 3) * NBKT + t];
        }
        for (; c < NCH; ++c) s0 += H[c * NBKT + t];
        tot = (s0 + s1) + (s2 + s3);
    }
    lds[t] = (t < NBKT) ? tot : 0;
    __syncthreads();
    for (int off = 1; off < 1024; off <<= 1) {
        int x = 0;
        if (t >= off) x = lds[t - off];
        __syncthreads();
        lds[t] += x;
        __syncthreads();
    }
    const int excl = lds[t] - tot;

    if (t < NBKT) {
        bkt_ptr[t] = excl;
        int run = excl;
        int c = 0;
        for (; c + 4 <= NCH; c += 4) {           // 4 loads in flight per step
            const int h0 = H[(c + 0) * NBKT + t];
            const int h1 = H[(c + 1) * NBKT + t];
            const int h2 = H[(c + 2) * NBKT + t];
            const int h3 = H[(c + 3) * NBKT + t];
            B[(c + 0) * NBKT + t] = run;
            B[(c + 1) * NBKT + t] = run + h0;
            B[(c + 2) * NBKT + t] = run + h0 + h1;
            B[(c + 3) * NBKT + t] = run + h0 + h1 + h2;
            run += h0 + h1 + h2 + h3;
        }
        for (; c < NCH; ++c) {
            B[c * NBKT + t] = run;
            run += H[c * NBKT + t];
        }
    }
    if (t == 0) bkt_ptr[NBKT] = N_EDGES;
}

// ===========================================================================
// Partition (single edge pass, no global atomics): pos = B[chunk][b] +
// ldsAtomicInc. 16 waves/block hide gather/scatter latency.
// record = (val, (localrow<<18)|col)
// ===========================================================================
__global__ __launch_bounds__(1024) void partition_l1(
    const float* __restrict__ vals, const int* __restrict__ rows,
    const int* __restrict__ cols, const int* __restrict__ B,
    float2* __restrict__ svc)
{
    __shared__ int base[NBKT];
    __shared__ int cnt[NBKT];
    const int t = threadIdx.x;
    const int c = blockIdx.x;
    if (t < NBKT) {
        base[t] = B[c * NBKT + t];
        cnt[t]  = 0;
    }
    __syncthreads();

    const int e0 = c * L1_CHUNK;
    const int e1 = (e0 + L1_CHUNK < N_EDGES) ? e0 + L1_CHUNK : N_EDGES;
    for (int i = e0 + t; i < e1; i += 1024) {
        const int r = rows[i];
        const int b = r >> RB_SHIFT;
        const int pos = base[b] + atomicAdd(&cnt[b], 1);
        const u32 packed = ((u32)(r & (RB - 1)) << 18) | (u32)cols[i];
        svc[pos] = make_float2(vals[i], __uint_as_float(packed));
    }
}

// ===========================================================================
// place_l2 (round-9 proven): per-row count (LDS) -> LDS scan -> row_ptr ->
// in-bucket placement via LDS heads.
// ===========================================================================
__global__ __launch_bounds__(256) void place_l2(
    const int* __restrict__ bkt_ptr, const float2* __restrict__ svc,
    float2* __restrict__ sedge, int* __restrict__ row_ptr)
{
    __shared__ int cnt[RB];
    __shared__ int heads[RB];
    const int b     = blockIdx.x;
    const int rbase = b << RB_SHIFT;
    const int t     = threadIdx.x;

    cnt[t] = 0;
    __syncthreads();

    const int lo = bkt_ptr[b];
    const int hi = bkt_ptr[b + 1];

    for (int i = lo + t; i < hi; i += 256)
        atomicAdd(&cnt[__float_as_uint(svc[i].y) >> 18], 1);
    __syncthreads();

    const int v = cnt[t];
    for (int off = 1; off < 256; off <<= 1) {
        int x = 0;
        if (t >= off) x = cnt[t - off];
        __syncthreads();
        cnt[t] += x;
        __syncthreads();
    }
    const int excl = cnt[t] - v;
    heads[t] = lo + excl;
    const int gr = rbase + t;
    if (gr <= N_NODES) row_ptr[gr] = lo + excl;
    __syncthreads();

    for (int i = lo + t; i < hi; i += 256) {
        const float2 vc = svc[i];
        const int lr  = (int)(__float_as_uint(vc.y) >> 18);
        const int pos = atomicAdd(&heads[lr], 1);
        sedge[pos] = vc;
    }
}

// ===========================================================================
// Pull-SpMM over bf16 source, dwordx2 gather: lane = (edge-slot g, dword-
// pair q). One VMEM instr fetches a full 128B row across 16 lanes -> 4
// edges per instruction, 8 edges in flight per iteration.
// ===========================================================================
__global__ __launch_bounds__(256) void spmm_bf16(
    const int* __restrict__ row_ptr,     // N_NODES+1
    const float2* __restrict__ sedge,    // (val, packed) row-sorted
    const u16* __restrict__ ebf,         // [N_NODES][64] bf16
    float* __restrict__ t_out)           // [N_NODES][64] f32
{
    const int tid  = threadIdx.x;
    const int lane = tid & 63;
    const int row  = blockIdx.x * 4 + (tid >> 6);
    if (row >= N_NODES) return;

    const int g = lane >> 4;    // edge slot 0..3
    const int q = lane & 15;    // dword pair -> features 4q..4q+3

    const int beg = row_ptr[row];
    const int end = row_ptr[row + 1];

    float a0 = 0.f, a1 = 0.f, a2 = 0.f, a3 = 0.f;

    int k = beg;
    for (; k + 8 <= end; k += 8) {
        const float2 mA = sedge[k + g];
        const float2 mB = sedge[k + 4 + g];
        const u32 iA = __float_as_uint(mA.y) & COL_MASK;
        const u32 iB = __float_as_uint(mB.y) & COL_MASK;
        const uint2 xA = *((const uint2*)(ebf + (size_t)iA * EMB) + q);
        const uint2 xB = *((const uint2*)(ebf + (size_t)iB * EMB) + q);
        a0 = fmaf(mA.x, bf16_lo(xA.x), a0);
        a1 = fmaf(mA.x, bf16_hi(xA.x), a1);
        a2 = fmaf(mA.x, bf16_lo(xA.y), a2);
        a3 = fmaf(mA.x, bf16_hi(xA.y), a3);
        a0 = fmaf(mB.x, bf16_lo(xB.x), a0);
        a1 = fmaf(mB.x, bf16_hi(xB.x), a1);
        a2 = fmaf(mB.x, bf16_lo(xB.y), a2);
        a3 = fmaf(mB.x, bf16_hi(xB.y), a3);
    }
    for (; k < end; k += 4) {        // tail: 4 slots, predicated
        const int  kk = k + g;
        const bool on = kk < end;
        const float2 m = sedge[on ? kk : (end - 1)];
        const float  v = on ? m.x : 0.f;
        const u32 ci = __float_as_uint(m.y) & COL_MASK;
        const uint2 x = *((const uint2*)(ebf + (size_t)ci * EMB) + q);
        a0 = fmaf(v, bf16_lo(x.x), a0);
        a1 = fmaf(v, bf16_hi(x.x), a1);
        a2 = fmaf(v, bf16_lo(x.y), a2);
        a3 = fmaf(v, bf16_hi(x.y), a3);
    }

    // reduce the 4 edge slots; lane q then holds features 4q..4q+3
    a0 += __shfl_xor(a0, 16); a0 += __shfl_xor(a0, 32);
    a1 += __shfl_xor(a1, 16); a1 += __shfl_xor(a1, 32);
    a2 += __shfl_xor(a2, 16); a2 += __shfl_xor(a2, 32);
    a3 += __shfl_xor(a3, 16); a3 += __shfl_xor(a3, 32);

    if (g == 0)
        *(float4*)(t_out + (size_t)row * EMB + 4 * q) =
            make_float4(a0, a1, a2, a3);
}

// ===========================================================================
// Dense stage: e_out = t @ W^T fused with LeakyReLU + 0.25-mean accumulation.
// FIRST also emits e2 as bf16 (stage-2 gather source). (round-8 proven)
// ===========================================================================
template <bool FIRST>
__global__ __launch_bounds__(256) void dense_stage(
    const float* __restrict__ t, const float* __restrict__ W,
    const float* __restrict__ user_emb, const float* __restrict__ item_emb,
    u16* __restrict__ e2bf, float* __restrict__ out)
{
    __shared__ float wT[64][65];
    __shared__ float trow[16][64];

    const int tid = threadIdx.x;
    for (int k = tid; k < 64 * 64; k += 256) {
        const int i = k >> 6, j = k & 63;
        wT[j][i] = W[k];
    }
    const int row_base = blockIdx.x * 16;
    for (int k = tid; k < 16 * 64; k += 256) {
        const int r = k >> 6, j = k & 63;
        const int row = row_base + r;
        trow[r][j] = (row < N_NODES) ? t[(size_t)row * EMB + j] : 0.f;
    }
    __syncthreads();

    const int i  = tid & 63;
    const int r0 = tid >> 6;

    #pragma unroll
    for (int rr = 0; rr < 4; ++rr) {
        const int r   = r0 * 4 + rr;
        const int row = row_base + r;
        if (row >= N_NODES) continue;

        float acc = 0.f;
        #pragma unroll
        for (int j = 0; j < 64; ++j)
            acc = fmaf(trow[r][j], wT[j][i], acc);

        const size_t idx = (size_t)row * EMB + i;
        if (FIRST) {
            const float e1v = acc;
            const float e2v = (e1v >= 0.f) ? e1v : LEAKY * e1v;
            const float e0v = (row < N_USERS)
                                  ? user_emb[idx]
                                  : item_emb[(size_t)(row - N_USERS) * EMB + i];
            e2bf[idx] = f32_to_bf16_rne(e2v);
            out[idx]  = 0.25f * (e0v + e1v + e2v);
        } else {
            out[idx] += 0.25f * acc;
        }
    }
}

// ===========================================================================
// Fallback (round-1 proven): atomic SpMM + f32 dense, if ws too small.
// ===========================================================================
__global__ __launch_bounds__(256) void spmm_atomic(
    const float* __restrict__ vals, const int* __restrict__ rows,
    const int* __restrict__ cols, const float* __restrict__ src_a,
    const float* __restrict__ src_b, float* __restrict__ dst)
{
    const int tid  = threadIdx.x;
    const int lane = tid & 63;
    const int e    = blockIdx.x * 4 + (tid >> 6);
    if (e >= N_EDGES) return;
    const float v = vals[e];
    const int   c = cols[e];
    const int   r = rows[e];
    const float* src = (src_b != nullptr && c >= N_USERS)
                           ? src_b + (size_t)(c - N_USERS) * EMB
                           : src_a + (size_t)c * EMB;
    unsafeAtomicAdd(&dst[(size_t)r * EMB + lane], v * src[lane]);
}

template <bool FIRST>
__global__ __launch_bounds__(256) void dense_f32(
    const float* __restrict__ t, const float* __restrict__ W,
    const float* __restrict__ user_emb, const float* __restrict__ item_emb,
    float* __restrict__ e2, float* __restrict__ out)
{
    __shared__ float wT[64][65];
    __shared__ float trow[16][64];

    const int tid = threadIdx.x;
    for (int k = tid; k < 64 * 64; k += 256) {
        const int i = k >> 6, j = k & 63;
        wT[j][i] = W[k];
    }
    const int row_base = blockIdx.x * 16;
    for (int k = tid; k < 16 * 64; k += 256) {
        const int r = k >> 6, j = k & 63;
        const int row = row_base + r;
        trow[r][j] = (row < N_NODES) ? t[(size_t)row * EMB + j] : 0.f;
    }
    __syncthreads();

    const int i  = tid & 63;
    const int r0 = tid >> 6;

    #pragma unroll
    for (int rr = 0; rr < 4; ++rr) {
        const int r   = r0 * 4 + rr;
        const int row = row_base + r;
        if (row >= N_NODES) continue;
        float acc = 0.f;
        #pragma unroll
        for (int j = 0; j < 64; ++j)
            acc = fmaf(trow[r][j], wT[j][i], acc);
        const size_t idx = (size_t)row * EMB + i;
        if (FIRST) {
            const float e1v = acc;
            const float e2v = (e1v >= 0.f) ? e1v : LEAKY * e1v;
            const float e0v = (row < N_USERS)
                                  ? user_emb[idx]
                                  : item_emb[(size_t)(row - N_USERS) * EMB + i];
            e2[idx]  = e2v;
            out[idx] = 0.25f * (e0v + e1v + e2v);
        } else {
            out[idx] += 0.25f * acc;
        }
    }
}

// ===========================================================================
extern "C" void kernel_launch(void* const* d_in, const int* in_sizes, int n_in,
                              void* d_out, int out_size, void* d_ws, size_t ws_size,
                              hipStream_t stream)
{
    const float* user_emb = (const float*)d_in[0];
    const float* item_emb = (const float*)d_in[1];
    const float* W0       = (const float*)d_in[2];
    const float* W1       = (const float*)d_in[3];
    const float* adj_vals = (const float*)d_in[4];
    const int*   adj_rows = (const int*)d_in[5];
    const int*   adj_cols = (const int*)d_in[6];
    float*       out      = (float*)d_out;

    const size_t mat_bytes = (size_t)N_NODES * EMB * sizeof(float);   // 38.4 MB
    const size_t ebf_bytes = (size_t)N_NODES * EMB * sizeof(u16);     // 19.2 MB
    const size_t edge8     = (size_t)N_EDGES * sizeof(float2);        // 19.2 MB
    const size_t hmat      = (size_t)NCH * NBKT * sizeof(int);        // 0.34 MB

    // layout: [t 38.4 | svc transient inside t] [sedge 19.2] [ebf 19.2] [aux]
    const size_t off_t      = 0;
    const size_t off_svc    = 0;                       // transient, inside t
    const size_t off_sedge  = off_t + mat_bytes;
    const size_t off_ebf    = off_sedge + edge8;
    const size_t off_rowptr = off_ebf + ebf_bytes;
    const size_t off_H      = off_rowptr + (size_t)(N_NODES + 1) * sizeof(int);
    const size_t off_B      = off_H + hmat;
    const size_t off_ptr    = off_B + hmat;
    const size_t required   = off_ptr + (size_t)(NBKT + 1) * sizeof(int); // ~78.3 MB

    const int dense_blocks = (N_NODES + 15) / 16;      // 9375
    const int spmm_blocks  = (N_NODES + 3) / 4;        // 37500
    const int conv_blocks  = (N_NODES * EMB / 4 + 255) / 256;

    if (ws_size >= required) {
        float*  t       = (float*)((char*)d_ws + off_t);
        float2* svc     = (float2*)((char*)d_ws + off_svc);
        float2* sedge   = (float2*)((char*)d_ws + off_sedge);
        u16*    ebf     = (u16*)((char*)d_ws + off_ebf);
        int*    row_ptr = (int*)((char*)d_ws + off_rowptr);
        int*    H       = (int*)((char*)d_ws + off_H);
        int*    B       = (int*)((char*)d_ws + off_B);
        int*    bkt_ptr = (int*)((char*)d_ws + off_ptr);

        // ---- bf16 source for stage 1 ----
        conv_e0<<<conv_blocks, 256, 0, stream>>>(user_emb, item_emb, ebf);

        // ---- bucket-sorted edge list + row_ptr (once, reused twice) ----
        bkt_hist<<<NCH, 1024, 0, stream>>>(adj_rows, H);
        scan_plus<<<1, 1024, 0, stream>>>(H, bkt_ptr, B);
        partition_l1<<<NCH, 1024, 0, stream>>>(
            adj_vals, adj_rows, adj_cols, B, svc);
        place_l2<<<NBKT, RB, 0, stream>>>(bkt_ptr, svc, sedge, row_ptr);
        // svc (inside t) is dead from here on

        // ---- stage 1: t = A @ e0 ; e1/e2/out ; e2 -> ebf (bf16) ----
        spmm_bf16<<<spmm_blocks, 256, 0, stream>>>(row_ptr, sedge, ebf, t);
        dense_stage<true><<<dense_blocks, 256, 0, stream>>>(
            t, W0, user_emb, item_emb, ebf, out);

        // ---- stage 2: t = A @ e2 ; out += 0.25*e3 ----
        spmm_bf16<<<spmm_blocks, 256, 0, stream>>>(row_ptr, sedge, ebf, t);
        dense_stage<false><<<dense_blocks, 256, 0, stream>>>(
            t, W1, nullptr, nullptr, nullptr, out);
    } else {
        // ---- fallback: round-1 atomic path ----
        float* t  = (float*)d_ws;
        float* e2 = (float*)((char*)d_ws + mat_bytes);

        hipMemsetAsync(t, 0, mat_bytes, stream);
        spmm_atomic<<<(N_EDGES + 3) / 4, 256, 0, stream>>>(
            adj_vals, adj_rows, adj_cols, user_emb, item_emb, t);
        dense_f32<true><<<dense_blocks, 256, 0, stream>>>(
            t, W0, user_emb, item_emb, e2, out);

        hipMemsetAsync(t, 0, mat_bytes, stream);
        spmm_atomic<<<(N_EDGES + 3) / 4, 256, 0, stream>>>(
            adj_vals, adj_rows, adj_cols, e2, nullptr, t);
        dense_f32<false><<<dense_blocks, 256, 0, stream>>>(
            t, W1, nullptr, nullptr, nullptr, out);
    }
}

// Round 12
// 251.129 us; speedup vs baseline: 1.6153x; 1.3139x over previous
//
#include <hip/hip_runtime.h>

#define N_USERS 100000
#define N_ITEMS 50000
#define N_NODES 150000
#define N_EDGES 2400000
#define EMB 64
#define LEAKY 0.3f

#define RB_SHIFT 8                                         // 256 rows / bucket
#define RB (1 << RB_SHIFT)
#define NBKT ((N_NODES + RB - 1) >> RB_SHIFT)              // 586
#define L1_CHUNK 16384
#define NCH ((N_EDGES + L1_CHUNK - 1) / L1_CHUNK)          // 147 chunks
#define COL_MASK 0x3FFFFu                                  // col < 2^18
#define NTILE (N_NODES / 16)                               // 9375 (exact)

typedef unsigned short u16;
typedef unsigned int   u32;
typedef __attribute__((ext_vector_type(8))) short short8v;
typedef __attribute__((ext_vector_type(4))) float f32x4;

__device__ __forceinline__ u16 f32_to_bf16_rne(float f) {
    u32 u = __float_as_uint(f);
    u32 r = (u + 0x7FFFu + ((u >> 16) & 1u)) >> 16;
    return (u16)r;
}
__device__ __forceinline__ float bf16_lo(u32 x) { return __uint_as_float(x << 16); }
__device__ __forceinline__ float bf16_hi(u32 x) { return __uint_as_float(x & 0xFFFF0000u); }

// ===========================================================================
// e0 -> bf16 (concatenated user ++ item), RNE
// ===========================================================================
__global__ __launch_bounds__(256) void conv_e0(
    const float* __restrict__ uemb, const float* __restrict__ iemb,
    u16* __restrict__ ebf)
{
    const int i = (blockIdx.x * 256 + threadIdx.x) * 4;
    if (i >= N_NODES * EMB) return;
    const float* src = (i < N_USERS * EMB) ? uemb + i : iemb + (i - N_USERS * EMB);
    const float4 v = *(const float4*)src;
    ushort4 w;
    w.x = f32_to_bf16_rne(v.x);
    w.y = f32_to_bf16_rne(v.y);
    w.z = f32_to_bf16_rne(v.z);
    w.w = f32_to_bf16_rne(v.w);
    *(ushort4*)(ebf + i) = w;
}

// W0,W1 -> bf16 (16 KB total, L2-resident for dense_mfma fragment loads)
__global__ __launch_bounds__(256) void conv_w(
    const float* __restrict__ W0, const float* __restrict__ W1,
    u16* __restrict__ Wbf0, u16* __restrict__ Wbf1)
{
    const int i = blockIdx.x * 256 + threadIdx.x;
    if (i < EMB * EMB) {
        Wbf0[i] = f32_to_bf16_rne(W0[i]);
        Wbf1[i] = f32_to_bf16_rne(W1[i]);
    }
}

// ===========================================================================
// Per-chunk bucket histogram -> H[chunk][NBKT] (no global atomics)
// ===========================================================================
__global__ __launch_bounds__(1024) void bkt_hist(
    const int* __restrict__ rows, int* __restrict__ H)
{
    __shared__ int cnt[NBKT];
    const int t = threadIdx.x;
    const int c = blockIdx.x;
    if (t < NBKT) cnt[t] = 0;
    __syncthreads();

    const int e0 = c * L1_CHUNK;
    const int e1 = (e0 + L1_CHUNK < N_EDGES) ? e0 + L1_CHUNK : N_EDGES;
    for (int i = e0 + t; i < e1; i += 1024)
        atomicAdd(&cnt[rows[i] >> RB_SHIFT], 1);
    __syncthreads();

    if (t < NBKT) H[c * NBKT + t] = cnt[t];
}

// ===========================================================================
// scan_plus (single block): bucket totals -> bkt_ptr; B[c][b] bases.
// ===========================================================================
__global__ __launch_bounds__(1024) void scan_plus(
    const int* __restrict__ H, int* __restrict__ bkt_ptr,
    int* __restrict__ B)
{
    __shared__ int lds[1024];
    const int t = threadIdx.x;

    int tot = 0;
    if (t < NBKT) {
        int s0 = 0, s1 = 0, s2 = 0, s3 = 0;
        int c = 0;
        for (; c + 4 <= NCH; c += 4) {
            s0 += H[(c + 0) * NBKT + t];
            s1 += H[(c + 1) * NBKT + t];
            s2 += H[(c + 2) * NBKT + t];
            s3 += H[(c + 3) * NBKT + t];
        }
        for (; c < NCH; ++c) s0 += H[c * NBKT + t];
        tot = (s0 + s1) + (s2 + s3);
    }
    lds[t] = (t < NBKT) ? tot : 0;
    __syncthreads();
    for (int off = 1; off < 1024; off <<= 1) {
        int x = 0;
        if (t >= off) x = lds[t - off];
        __syncthreads();
        lds[t] += x;
        __syncthreads();
    }
    const int excl = lds[t] - tot;

    if (t < NBKT) {
        bkt_ptr[t] = excl;
        int run = excl;
        int c = 0;
        for (; c + 4 <= NCH; c += 4) {
            const int h0 = H[(c + 0) * NBKT + t];
            const int h1 = H[(c + 1) * NBKT + t];
            const int h2 = H[(c + 2) * NBKT + t];
            const int h3 = H[(c + 3) * NBKT + t];
            B[(c + 0) * NBKT + t] = run;
            B[(c + 1) * NBKT + t] = run + h0;
            B[(c + 2) * NBKT + t] = run + h0 + h1;
            B[(c + 3) * NBKT + t] = run + h0 + h1 + h2;
            run += h0 + h1 + h2 + h3;
        }
        for (; c < NCH; ++c) {
            B[c * NBKT + t] = run;
            run += H[c * NBKT + t];
        }
    }
    if (t == 0) bkt_ptr[NBKT] = N_EDGES;
}

// ===========================================================================
// Partition (single edge pass, no global atomics)
// ===========================================================================
__global__ __launch_bounds__(1024) void partition_l1(
    const float* __restrict__ vals, const int* __restrict__ rows,
    const int* __restrict__ cols, const int* __restrict__ B,
    float2* __restrict__ svc)
{
    __shared__ int base[NBKT];
    __shared__ int cnt[NBKT];
    const int t = threadIdx.x;
    const int c = blockIdx.x;
    if (t < NBKT) {
        base[t] = B[c * NBKT + t];
        cnt[t]  = 0;
    }
    __syncthreads();

    const int e0 = c * L1_CHUNK;
    const int e1 = (e0 + L1_CHUNK < N_EDGES) ? e0 + L1_CHUNK : N_EDGES;
    for (int i = e0 + t; i < e1; i += 1024) {
        const int r = rows[i];
        const int b = r >> RB_SHIFT;
        const int pos = base[b] + atomicAdd(&cnt[b], 1);
        const u32 packed = ((u32)(r & (RB - 1)) << 18) | (u32)cols[i];
        svc[pos] = make_float2(vals[i], __uint_as_float(packed));
    }
}

// ===========================================================================
// place_l2 (round-9 proven)
// ===========================================================================
__global__ __launch_bounds__(256) void place_l2(
    const int* __restrict__ bkt_ptr, const float2* __restrict__ svc,
    float2* __restrict__ sedge, int* __restrict__ row_ptr)
{
    __shared__ int cnt[RB];
    __shared__ int heads[RB];
    const int b     = blockIdx.x;
    const int rbase = b << RB_SHIFT;
    const int t     = threadIdx.x;

    cnt[t] = 0;
    __syncthreads();

    const int lo = bkt_ptr[b];
    const int hi = bkt_ptr[b + 1];

    for (int i = lo + t; i < hi; i += 256)
        atomicAdd(&cnt[__float_as_uint(svc[i].y) >> 18], 1);
    __syncthreads();

    const int v = cnt[t];
    for (int off = 1; off < 256; off <<= 1) {
        int x = 0;
        if (t >= off) x = cnt[t - off];
        __syncthreads();
        cnt[t] += x;
        __syncthreads();
    }
    const int excl = cnt[t] - v;
    heads[t] = lo + excl;
    const int gr = rbase + t;
    if (gr <= N_NODES) row_ptr[gr] = lo + excl;
    __syncthreads();

    for (int i = lo + t; i < hi; i += 256) {
        const float2 vc = svc[i];
        const int lr  = (int)(__float_as_uint(vc.y) >> 18);
        const int pos = atomicAdd(&heads[lr], 1);
        sedge[pos] = vc;
    }
}

// ===========================================================================
// Pull-SpMM over bf16 source, dwordx2 gather (round-11 proven), now writing
// t as bf16 (halves write traffic + dense read traffic).
// ===========================================================================
__global__ __launch_bounds__(256) void spmm_bf16(
    const int* __restrict__ row_ptr,
    const float2* __restrict__ sedge,
    const u16* __restrict__ ebf,
    u16* __restrict__ tbf)               // [N_NODES][64] bf16
{
    const int tid  = threadIdx.x;
    const int lane = tid & 63;
    const int row  = blockIdx.x * 4 + (tid >> 6);
    if (row >= N_NODES) return;

    const int g = lane >> 4;    // edge slot 0..3
    const int q = lane & 15;    // dword pair -> features 4q..4q+3

    const int beg = row_ptr[row];
    const int end = row_ptr[row + 1];

    float a0 = 0.f, a1 = 0.f, a2 = 0.f, a3 = 0.f;

    int k = beg;
    for (; k + 8 <= end; k += 8) {
        const float2 mA = sedge[k + g];
        const float2 mB = sedge[k + 4 + g];
        const u32 iA = __float_as_uint(mA.y) & COL_MASK;
        const u32 iB = __float_as_uint(mB.y) & COL_MASK;
        const uint2 xA = *((const uint2*)(ebf + (size_t)iA * EMB) + q);
        const uint2 xB = *((const uint2*)(ebf + (size_t)iB * EMB) + q);
        a0 = fmaf(mA.x, bf16_lo(xA.x), a0);
        a1 = fmaf(mA.x, bf16_hi(xA.x), a1);
        a2 = fmaf(mA.x, bf16_lo(xA.y), a2);
        a3 = fmaf(mA.x, bf16_hi(xA.y), a3);
        a0 = fmaf(mB.x, bf16_lo(xB.x), a0);
        a1 = fmaf(mB.x, bf16_hi(xB.x), a1);
        a2 = fmaf(mB.x, bf16_lo(xB.y), a2);
        a3 = fmaf(mB.x, bf16_hi(xB.y), a3);
    }
    for (; k < end; k += 4) {
        const int  kk = k + g;
        const bool on = kk < end;
        const float2 m = sedge[on ? kk : (end - 1)];
        const float  v = on ? m.x : 0.f;
        const u32 ci = __float_as_uint(m.y) & COL_MASK;
        const uint2 x = *((const uint2*)(ebf + (size_t)ci * EMB) + q);
        a0 = fmaf(v, bf16_lo(x.x), a0);
        a1 = fmaf(v, bf16_hi(x.x), a1);
        a2 = fmaf(v, bf16_lo(x.y), a2);
        a3 = fmaf(v, bf16_hi(x.y), a3);
    }

    a0 += __shfl_xor(a0, 16); a0 += __shfl_xor(a0, 32);
    a1 += __shfl_xor(a1, 16); a1 += __shfl_xor(a1, 32);
    a2 += __shfl_xor(a2, 16); a2 += __shfl_xor(a2, 32);
    a3 += __shfl_xor(a3, 16); a3 += __shfl_xor(a3, 32);

    if (g == 0) {
        ushort4 w4;
        w4.x = f32_to_bf16_rne(a0);
        w4.y = f32_to_bf16_rne(a1);
        w4.z = f32_to_bf16_rne(a2);
        w4.w = f32_to_bf16_rne(a3);
        *(ushort4*)(tbf + (size_t)row * EMB + 4 * q) = w4;
    }
}

// ===========================================================================
// Dense stage via MFMA: e1 = t @ W^T (M=150000, N=64, K=64), fused with
// LeakyReLU + e0-add + 0.25-mean + e2->bf16 writeback. One 16-row tile per
// wave, 8x mfma_f32_16x16x32_bf16, no LDS.
// A frag: t[row0+(l&15)][32*kh + 8*(l>>4)+e]      (16B contiguous)
// B frag: B[k][col]=W[col][k] -> W[16c+(l&15)][32*kh + 8*(l>>4)+e]
// D:      row = 4*(l>>4)+reg, col = 16c+(l&15)    (m89-verified layout)
// ===========================================================================
template <bool FIRST>
__global__ __launch_bounds__(256) void dense_mfma(
    const u16* __restrict__ tbf,     // [N_NODES][64] bf16
    const u16* __restrict__ Wbf,     // [64][64] bf16
    u16* ebf,                        // FIRST: e0 read + e2 write (same elem)
    float* __restrict__ out)
{
    const int tid  = threadIdx.x;
    const int l    = tid & 63;
    const int tile = blockIdx.x * 4 + (tid >> 6);
    if (tile >= NTILE) return;
    const int row0 = tile * 16;

    const int lr = l & 15;
    const int lk = l >> 4;

    short8v bfrag[4][2];
    #pragma unroll
    for (int c = 0; c < 4; ++c)
        #pragma unroll
        for (int kh = 0; kh < 2; ++kh)
            bfrag[c][kh] = *(const short8v*)(Wbf + (size_t)(16 * c + lr) * EMB
                                             + 32 * kh + 8 * lk);

    const u16* trow = tbf + (size_t)(row0 + lr) * EMB;
    const short8v afrag0 = *(const short8v*)(trow + 8 * lk);
    const short8v afrag1 = *(const short8v*)(trow + 32 + 8 * lk);

    f32x4 acc[4];
    #pragma unroll
    for (int c = 0; c < 4; ++c) {
        f32x4 z = {0.f, 0.f, 0.f, 0.f};
        z = __builtin_amdgcn_mfma_f32_16x16x32_bf16(afrag0, bfrag[c][0], z, 0, 0, 0);
        z = __builtin_amdgcn_mfma_f32_16x16x32_bf16(afrag1, bfrag[c][1], z, 0, 0, 0);
        acc[c] = z;
    }

    #pragma unroll
    for (int c = 0; c < 4; ++c) {
        #pragma unroll
        for (int r = 0; r < 4; ++r) {
            const int row = row0 + 4 * lk + r;
            const size_t idx = (size_t)row * EMB + 16 * c + lr;
            const float e1v = acc[c][r];
            if (FIRST) {
                const float e2v = (e1v >= 0.f) ? e1v : LEAKY * e1v;
                const float e0v = bf16_lo((u32)ebf[idx]);   // e0 (bf16)
                out[idx] = 0.25f * (e0v + e1v + e2v);
                ebf[idx] = f32_to_bf16_rne(e2v);            // e2 for stage 2
            } else {
                out[idx] += 0.25f * e1v;
            }
        }
    }
}

// ===========================================================================
// Fallback (round-1 proven): atomic SpMM + f32 dense, if ws too small.
// ===========================================================================
__global__ __launch_bounds__(256) void spmm_atomic(
    const float* __restrict__ vals, const int* __restrict__ rows,
    const int* __restrict__ cols, const float* __restrict__ src_a,
    const float* __restrict__ src_b, float* __restrict__ dst)
{
    const int tid  = threadIdx.x;
    const int lane = tid & 63;
    const int e    = blockIdx.x * 4 + (tid >> 6);
    if (e >= N_EDGES) return;
    const float v = vals[e];
    const int   c = cols[e];
    const int   r = rows[e];
    const float* src = (src_b != nullptr && c >= N_USERS)
                           ? src_b + (size_t)(c - N_USERS) * EMB
                           : src_a + (size_t)c * EMB;
    unsafeAtomicAdd(&dst[(size_t)r * EMB + lane], v * src[lane]);
}

template <bool FIRST>
__global__ __launch_bounds__(256) void dense_f32(
    const float* __restrict__ t, const float* __restrict__ W,
    const float* __restrict__ user_emb, const float* __restrict__ item_emb,
    float* __restrict__ e2, float* __restrict__ out)
{
    __shared__ float wT[64][65];
    __shared__ float trow[16][64];

    const int tid = threadIdx.x;
    for (int k = tid; k < 64 * 64; k += 256) {
        const int i = k >> 6, j = k & 63;
        wT[j][i] = W[k];
    }
    const int row_base = blockIdx.x * 16;
    for (int k = tid; k < 16 * 64; k += 256) {
        const int r = k >> 6, j = k & 63;
        const int row = row_base + r;
        trow[r][j] = (row < N_NODES) ? t[(size_t)row * EMB + j] : 0.f;
    }
    __syncthreads();

    const int i  = tid & 63;
    const int r0 = tid >> 6;

    #pragma unroll
    for (int rr = 0; rr < 4; ++rr) {
        const int r   = r0 * 4 + rr;
        const int row = row_base + r;
        if (row >= N_NODES) continue;
        float acc = 0.f;
        #pragma unroll
        for (int j = 0; j < 64; ++j)
            acc = fmaf(trow[r][j], wT[j][i], acc);
        const size_t idx = (size_t)row * EMB + i;
        if (FIRST) {
            const float e1v = acc;
            const float e2v = (e1v >= 0.f) ? e1v : LEAKY * e1v;
            const float e0v = (row < N_USERS)
                                  ? user_emb[idx]
                                  : item_emb[(size_t)(row - N_USERS) * EMB + i];
            e2[idx]  = e2v;
            out[idx] = 0.25f * (e0v + e1v + e2v);
        } else {
            out[idx] += 0.25f * acc;
        }
    }
}

// ===========================================================================
extern "C" void kernel_launch(void* const* d_in, const int* in_sizes, int n_in,
                              void* d_out, int out_size, void* d_ws, size_t ws_size,
                              hipStream_t stream)
{
    const float* user_emb = (const float*)d_in[0];
    const float* item_emb = (const float*)d_in[1];
    const float* W0       = (const float*)d_in[2];
    const float* W1       = (const float*)d_in[3];
    const float* adj_vals = (const float*)d_in[4];
    const int*   adj_rows = (const int*)d_in[5];
    const int*   adj_cols = (const int*)d_in[6];
    float*       out      = (float*)d_out;

    const size_t mat_bytes = (size_t)N_NODES * EMB * sizeof(float);   // 38.4 MB
    const size_t ebf_bytes = (size_t)N_NODES * EMB * sizeof(u16);     // 19.2 MB
    const size_t edge8     = (size_t)N_EDGES * sizeof(float2);        // 19.2 MB
    const size_t hmat      = (size_t)NCH * NBKT * sizeof(int);

    // layout: [tbf 19.2 | svc transient] [sedge 19.2] [ebf 19.2] [aux] [Wbf]
    const size_t off_tbf    = 0;
    const size_t off_svc    = 0;                       // transient, inside tbf
    const size_t off_sedge  = off_tbf + ebf_bytes;
    const size_t off_ebf    = off_sedge + edge8;
    const size_t off_rowptr = off_ebf + ebf_bytes;
    const size_t off_H      = off_rowptr + (size_t)(N_NODES + 1) * sizeof(int);
    const size_t off_B      = off_H + hmat;
    const size_t off_ptr    = off_B + hmat;
    const size_t off_wbf    = (off_ptr + (size_t)(NBKT + 1) * sizeof(int) + 15) & ~(size_t)15;
    const size_t required   = off_wbf + 2 * (size_t)EMB * EMB * sizeof(u16); // ~59.5 MB

    const int spmm_blocks   = (N_NODES + 3) / 4;       // 37500
    const int densem_blocks = (NTILE + 3) / 4;         // 2344
    const int conv_blocks   = (N_NODES * EMB / 4 + 255) / 256;

    if (ws_size >= required) {
        u16*    tbf     = (u16*)((char*)d_ws + off_tbf);
        float2* svc     = (float2*)((char*)d_ws + off_svc);
        float2* sedge   = (float2*)((char*)d_ws + off_sedge);
        u16*    ebf     = (u16*)((char*)d_ws + off_ebf);
        int*    row_ptr = (int*)((char*)d_ws + off_rowptr);
        int*    H       = (int*)((char*)d_ws + off_H);
        int*    B       = (int*)((char*)d_ws + off_B);
        int*    bkt_ptr = (int*)((char*)d_ws + off_ptr);
        u16*    Wbf0    = (u16*)((char*)d_ws + off_wbf);
        u16*    Wbf1    = Wbf0 + EMB * EMB;

        // ---- bf16 sources ----
        conv_e0<<<conv_blocks, 256, 0, stream>>>(user_emb, item_emb, ebf);
        conv_w<<<(EMB * EMB + 255) / 256, 256, 0, stream>>>(W0, W1, Wbf0, Wbf1);

        // ---- bucket-sorted edge list + row_ptr (once, reused twice) ----
        bkt_hist<<<NCH, 1024, 0, stream>>>(adj_rows, H);
        scan_plus<<<1, 1024, 0, stream>>>(H, bkt_ptr, B);
        partition_l1<<<NCH, 1024, 0, stream>>>(
            adj_vals, adj_rows, adj_cols, B, svc);
        place_l2<<<NBKT, RB, 0, stream>>>(bkt_ptr, svc, sedge, row_ptr);
        // svc (inside tbf) is dead from here on

        // ---- stage 1: tbf = A @ e0 ; e1/e2/out ; e2 -> ebf (bf16) ----
        spmm_bf16<<<spmm_blocks, 256, 0, stream>>>(row_ptr, sedge, ebf, tbf);
        dense_mfma<true><<<densem_blocks, 256, 0, stream>>>(tbf, Wbf0, ebf, out);

        // ---- stage 2: tbf = A @ e2 ; out += 0.25*e3 ----
        spmm_bf16<<<spmm_blocks, 256, 0, stream>>>(row_ptr, sedge, ebf, tbf);
        dense_mfma<false><<<densem_blocks, 256, 0, stream>>>(tbf, Wbf1, ebf, out);
    } else {
        // ---- fallback: round-1 atomic path ----
        float* t  = (float*)d_ws;
        float* e2 = (float*)((char*)d_ws + mat_bytes);
        const int dense_blocks = (N_NODES + 15) / 16;

        hipMemsetAsync(t, 0, mat_bytes, stream);
        spmm_atomic<<<(N_EDGES + 3) / 4, 256, 0, stream>>>(
            adj_vals, adj_rows, adj_cols, user_emb, item_emb, t);
        dense_f32<true><<<dense_blocks, 256, 0, stream>>>(
            t, W0, user_emb, item_emb, e2, out);

        hipMemsetAsync(t, 0, mat_bytes, stream);
        spmm_atomic<<<(N_EDGES + 3) / 4, 256, 0, stream>>>(
            adj_vals, adj_rows, adj_cols, e2, nullptr, t);
        dense_f32<false><<<dense_blocks, 256, 0, stream>>>(
            t, W1, nullptr, nullptr, nullptr, out);
    }
}

// Round 13
// 232.591 us; speedup vs baseline: 1.7440x; 1.0797x over previous
//
#include <hip/hip_runtime.h>

#define N_USERS 100000
#define N_ITEMS 50000
#define N_NODES 150000
#define N_EDGES 2400000
#define EMB 64
#define LEAKY 0.3f

#define RB_SHIFT 8                                         // 256 rows / bucket
#define RB (1 << RB_SHIFT)
#define NBKT ((N_NODES + RB - 1) >> RB_SHIFT)              // 586
#define L1_CHUNK 16384
#define NCH ((N_EDGES + L1_CHUNK - 1) / L1_CHUNK)          // 147 chunks
#define COL_MASK 0x3FFFFu                                  // col < 2^18
#define NTILE (N_NODES / 16)                               // 9375 (exact)

typedef unsigned short u16;
typedef unsigned int   u32;
typedef __attribute__((ext_vector_type(8))) short short8v;
typedef __attribute__((ext_vector_type(4))) float f32x4;

__device__ __forceinline__ u16 f32_to_bf16_rne(float f) {
    u32 u = __float_as_uint(f);
    u32 r = (u + 0x7FFFu + ((u >> 16) & 1u)) >> 16;
    return (u16)r;
}
__device__ __forceinline__ float bf16_lo(u32 x) { return __uint_as_float(x << 16); }
__device__ __forceinline__ float bf16_hi(u32 x) { return __uint_as_float(x & 0xFFFF0000u); }
__device__ __forceinline__ u32 pack_bf16(float lo, float hi) {
    return (u32)f32_to_bf16_rne(lo) | ((u32)f32_to_bf16_rne(hi) << 16);
}

// ===========================================================================
// e0 -> bf16 (user ++ item) and W0/W1 -> bf16, one dispatch
// ===========================================================================
__global__ __launch_bounds__(256) void conv_all(
    const float* __restrict__ uemb, const float* __restrict__ iemb,
    const float* __restrict__ W0, const float* __restrict__ W1,
    u16* __restrict__ ebf, u16* __restrict__ Wbf0, u16* __restrict__ Wbf1)
{
    const int gid = blockIdx.x * 256 + threadIdx.x;
    const int i = gid * 4;
    if (i < N_NODES * EMB) {
        const float* src = (i < N_USERS * EMB) ? uemb + i : iemb + (i - N_USERS * EMB);
        const float4 v = *(const float4*)src;
        ushort4 w;
        w.x = f32_to_bf16_rne(v.x);
        w.y = f32_to_bf16_rne(v.y);
        w.z = f32_to_bf16_rne(v.z);
        w.w = f32_to_bf16_rne(v.w);
        *(ushort4*)(ebf + i) = w;
    }
    if (gid < EMB * EMB) {
        Wbf0[gid] = f32_to_bf16_rne(W0[gid]);
        Wbf1[gid] = f32_to_bf16_rne(W1[gid]);
    }
}

// ===========================================================================
// Per-chunk bucket histogram -> H[chunk][NBKT] (no global atomics)
// ===========================================================================
__global__ __launch_bounds__(1024) void bkt_hist(
    const int* __restrict__ rows, int* __restrict__ H)
{
    __shared__ int cnt[NBKT];
    const int t = threadIdx.x;
    const int c = blockIdx.x;
    if (t < NBKT) cnt[t] = 0;
    __syncthreads();

    const int e0 = c * L1_CHUNK;
    const int e1 = (e0 + L1_CHUNK < N_EDGES) ? e0 + L1_CHUNK : N_EDGES;
    for (int i = e0 + t; i < e1; i += 1024)
        atomicAdd(&cnt[rows[i] >> RB_SHIFT], 1);
    __syncthreads();

    if (t < NBKT) H[c * NBKT + t] = cnt[t];
}

// ===========================================================================
// scan_plus (single block): bucket totals -> bkt_ptr; B[c][b] bases.
// ===========================================================================
__global__ __launch_bounds__(1024) void scan_plus(
    const int* __restrict__ H, int* __restrict__ bkt_ptr,
    int* __restrict__ B)
{
    __shared__ int lds[1024];
    const int t = threadIdx.x;

    int tot = 0;
    if (t < NBKT) {
        int s0 = 0, s1 = 0, s2 = 0, s3 = 0;
        int c = 0;
        for (; c + 4 <= NCH; c += 4) {
            s0 += H[(c + 0) * NBKT + t];
            s1 += H[(c + 1) * NBKT + t];
            s2 += H[(c + 2) * NBKT + t];
            s3 += H[(c + 3) * NBKT + t];
        }
        for (; c < NCH; ++c) s0 += H[c * NBKT + t];
        tot = (s0 + s1) + (s2 + s3);
    }
    lds[t] = (t < NBKT) ? tot : 0;
    __syncthreads();
    for (int off = 1; off < 1024; off <<= 1) {
        int x = 0;
        if (t >= off) x = lds[t - off];
        __syncthreads();
        lds[t] += x;
        __syncthreads();
    }
    const int excl = lds[t] - tot;

    if (t < NBKT) {
        bkt_ptr[t] = excl;
        int run = excl;
        int c = 0;
        for (; c + 4 <= NCH; c += 4) {
            const int h0 = H[(c + 0) * NBKT + t];
            const int h1 = H[(c + 1) * NBKT + t];
            const int h2 = H[(c + 2) * NBKT + t];
            const int h3 = H[(c + 3) * NBKT + t];
            B[(c + 0) * NBKT + t] = run;
            B[(c + 1) * NBKT + t] = run + h0;
            B[(c + 2) * NBKT + t] = run + h0 + h1;
            B[(c + 3) * NBKT + t] = run + h0 + h1 + h2;
            run += h0 + h1 + h2 + h3;
        }
        for (; c < NCH; ++c) {
            B[c * NBKT + t] = run;
            run += H[c * NBKT + t];
        }
    }
    if (t == 0) bkt_ptr[NBKT] = N_EDGES;
}

// ===========================================================================
// Partition (single edge pass, no global atomics)
// ===========================================================================
__global__ __launch_bounds__(1024) void partition_l1(
    const float* __restrict__ vals, const int* __restrict__ rows,
    const int* __restrict__ cols, const int* __restrict__ B,
    float2* __restrict__ svc)
{
    __shared__ int base[NBKT];
    __shared__ int cnt[NBKT];
    const int t = threadIdx.x;
    const int c = blockIdx.x;
    if (t < NBKT) {
        base[t] = B[c * NBKT + t];
        cnt[t]  = 0;
    }
    __syncthreads();

    const int e0 = c * L1_CHUNK;
    const int e1 = (e0 + L1_CHUNK < N_EDGES) ? e0 + L1_CHUNK : N_EDGES;
    for (int i = e0 + t; i < e1; i += 1024) {
        const int r = rows[i];
        const int b = r >> RB_SHIFT;
        const int pos = base[b] + atomicAdd(&cnt[b], 1);
        const u32 packed = ((u32)(r & (RB - 1)) << 18) | (u32)cols[i];
        svc[pos] = make_float2(vals[i], __uint_as_float(packed));
    }
}

// ===========================================================================
// place_l2 (round-9 proven)
// ===========================================================================
__global__ __launch_bounds__(256) void place_l2(
    const int* __restrict__ bkt_ptr, const float2* __restrict__ svc,
    float2* __restrict__ sedge, int* __restrict__ row_ptr)
{
    __shared__ int cnt[RB];
    __shared__ int heads[RB];
    const int b     = blockIdx.x;
    const int rbase = b << RB_SHIFT;
    const int t     = threadIdx.x;

    cnt[t] = 0;
    __syncthreads();

    const int lo = bkt_ptr[b];
    const int hi = bkt_ptr[b + 1];

    for (int i = lo + t; i < hi; i += 256)
        atomicAdd(&cnt[__float_as_uint(svc[i].y) >> 18], 1);
    __syncthreads();

    const int v = cnt[t];
    for (int off = 1; off < 256; off <<= 1) {
        int x = 0;
        if (t >= off) x = cnt[t - off];
        __syncthreads();
        cnt[t] += x;
        __syncthreads();
    }
    const int excl = cnt[t] - v;
    heads[t] = lo + excl;
    const int gr = rbase + t;
    if (gr <= N_NODES) row_ptr[gr] = lo + excl;
    __syncthreads();

    for (int i = lo + t; i < hi; i += 256) {
        const float2 vc = svc[i];
        const int lr  = (int)(__float_as_uint(vc.y) >> 18);
        const int pos = atomicAdd(&heads[lr], 1);
        sedge[pos] = vc;
    }
}

// ===========================================================================
// Pull-SpMM over bf16 source, dwordx4 gather: lane = (edge-slot g = lane>>3,
// feature-octet q = lane&7). One VMEM instr fetches 8 full 128B rows across
// the wave; 16 edges (2 gathers) in flight per iteration.
// ===========================================================================
__global__ __launch_bounds__(256) void spmm_bf16(
    const int* __restrict__ row_ptr,     // N_NODES+1
    const float2* __restrict__ sedge,    // (val, packed) row-sorted
    const u16* __restrict__ ebf,         // [N_NODES][64] bf16
    u16* __restrict__ tbf)               // [N_NODES][64] bf16
{
    const int tid  = threadIdx.x;
    const int lane = tid & 63;
    const int row  = blockIdx.x * 4 + (tid >> 6);
    if (row >= N_NODES) return;

    const int g = lane >> 3;    // edge slot 0..7
    const int q = lane & 7;     // feature octet -> features 8q..8q+7

    const int beg = row_ptr[row];
    const int end = row_ptr[row + 1];

    float a0 = 0.f, a1 = 0.f, a2 = 0.f, a3 = 0.f;
    float a4 = 0.f, a5 = 0.f, a6 = 0.f, a7 = 0.f;

    int k = beg;
    for (; k + 16 <= end; k += 16) {
        const float2 mA = sedge[k + g];
        const float2 mB = sedge[k + 8 + g];
        const u32 iA = __float_as_uint(mA.y) & COL_MASK;
        const u32 iB = __float_as_uint(mB.y) & COL_MASK;
        const uint4 xA = *((const uint4*)(ebf + (size_t)iA * EMB) + q);
        const uint4 xB = *((const uint4*)(ebf + (size_t)iB * EMB) + q);
        a0 = fmaf(mA.x, bf16_lo(xA.x), a0);
        a1 = fmaf(mA.x, bf16_hi(xA.x), a1);
        a2 = fmaf(mA.x, bf16_lo(xA.y), a2);
        a3 = fmaf(mA.x, bf16_hi(xA.y), a3);
        a4 = fmaf(mA.x, bf16_lo(xA.z), a4);
        a5 = fmaf(mA.x, bf16_hi(xA.z), a5);
        a6 = fmaf(mA.x, bf16_lo(xA.w), a6);
        a7 = fmaf(mA.x, bf16_hi(xA.w), a7);
        a0 = fmaf(mB.x, bf16_lo(xB.x), a0);
        a1 = fmaf(mB.x, bf16_hi(xB.x), a1);
        a2 = fmaf(mB.x, bf16_lo(xB.y), a2);
        a3 = fmaf(mB.x, bf16_hi(xB.y), a3);
        a4 = fmaf(mB.x, bf16_lo(xB.z), a4);
        a5 = fmaf(mB.x, bf16_hi(xB.z), a5);
        a6 = fmaf(mB.x, bf16_lo(xB.w), a6);
        a7 = fmaf(mB.x, bf16_hi(xB.w), a7);
    }
    for (; k < end; k += 8) {      // tail: 8 predicated slots per pass
        const int  kk = k + g;
        const bool on = kk < end;
        const float2 m = sedge[on ? kk : (end - 1)];
        const float  v = on ? m.x : 0.f;
        const u32 ci = __float_as_uint(m.y) & COL_MASK;
        const uint4 x = *((const uint4*)(ebf + (size_t)ci * EMB) + q);
        a0 = fmaf(v, bf16_lo(x.x), a0);
        a1 = fmaf(v, bf16_hi(x.x), a1);
        a2 = fmaf(v, bf16_lo(x.y), a2);
        a3 = fmaf(v, bf16_hi(x.y), a3);
        a4 = fmaf(v, bf16_lo(x.z), a4);
        a5 = fmaf(v, bf16_hi(x.z), a5);
        a6 = fmaf(v, bf16_lo(x.w), a6);
        a7 = fmaf(v, bf16_hi(x.w), a7);
    }

    // reduce across the 8 edge slots (xor 8,16,32)
    a0 += __shfl_xor(a0, 8); a0 += __shfl_xor(a0, 16); a0 += __shfl_xor(a0, 32);
    a1 += __shfl_xor(a1, 8); a1 += __shfl_xor(a1, 16); a1 += __shfl_xor(a1, 32);
    a2 += __shfl_xor(a2, 8); a2 += __shfl_xor(a2, 16); a2 += __shfl_xor(a2, 32);
    a3 += __shfl_xor(a3, 8); a3 += __shfl_xor(a3, 16); a3 += __shfl_xor(a3, 32);
    a4 += __shfl_xor(a4, 8); a4 += __shfl_xor(a4, 16); a4 += __shfl_xor(a4, 32);
    a5 += __shfl_xor(a5, 8); a5 += __shfl_xor(a5, 16); a5 += __shfl_xor(a5, 32);
    a6 += __shfl_xor(a6, 8); a6 += __shfl_xor(a6, 16); a6 += __shfl_xor(a6, 32);
    a7 += __shfl_xor(a7, 8); a7 += __shfl_xor(a7, 16); a7 += __shfl_xor(a7, 32);

    if (g == 0) {
        uint4 w;
        w.x = pack_bf16(a0, a1);
        w.y = pack_bf16(a2, a3);
        w.z = pack_bf16(a4, a5);
        w.w = pack_bf16(a6, a7);
        *(uint4*)(tbf + (size_t)row * EMB + 8 * q) = w;
    }
}

// ===========================================================================
// Dense stage via MFMA (round-12 proven): e1 = t @ W^T fused with LeakyReLU
// + e0-add + 0.25-mean + e2->bf16 writeback. 8x mfma_16x16x32_bf16, no LDS.
// ===========================================================================
template <bool FIRST>
__global__ __launch_bounds__(256) void dense_mfma(
    const u16* __restrict__ tbf,     // [N_NODES][64] bf16
    const u16* __restrict__ Wbf,     // [64][64] bf16
    u16* ebf,                        // FIRST: e0 read + e2 write (same elem)
    float* __restrict__ out)
{
    const int tid  = threadIdx.x;
    const int l    = tid & 63;
    const int tile = blockIdx.x * 4 + (tid >> 6);
    if (tile >= NTILE) return;
    const int row0 = tile * 16;

    const int lr = l & 15;
    const int lk = l >> 4;

    short8v bfrag[4][2];
    #pragma unroll
    for (int c = 0; c < 4; ++c)
        #pragma unroll
        for (int kh = 0; kh < 2; ++kh)
            bfrag[c][kh] = *(const short8v*)(Wbf + (size_t)(16 * c + lr) * EMB
                                             + 32 * kh + 8 * lk);

    const u16* trow = tbf + (size_t)(row0 + lr) * EMB;
    const short8v afrag0 = *(const short8v*)(trow + 8 * lk);
    const short8v afrag1 = *(const short8v*)(trow + 32 + 8 * lk);

    f32x4 acc[4];
    #pragma unroll
    for (int c = 0; c < 4; ++c) {
        f32x4 z = {0.f, 0.f, 0.f, 0.f};
        z = __builtin_amdgcn_mfma_f32_16x16x32_bf16(afrag0, bfrag[c][0], z, 0, 0, 0);
        z = __builtin_amdgcn_mfma_f32_16x16x32_bf16(afrag1, bfrag[c][1], z, 0, 0, 0);
        acc[c] = z;
    }

    #pragma unroll
    for (int c = 0; c < 4; ++c) {
        #pragma unroll
        for (int r = 0; r < 4; ++r) {
            const int row = row0 + 4 * lk + r;
            const size_t idx = (size_t)row * EMB + 16 * c + lr;
            const float e1v = acc[c][r];
            if (FIRST) {
                const float e2v = (e1v >= 0.f) ? e1v : LEAKY * e1v;
                const float e0v = bf16_lo((u32)ebf[idx]);   // e0 (bf16)
                out[idx] = 0.25f * (e0v + e1v + e2v);
                ebf[idx] = f32_to_bf16_rne(e2v);            // e2 for stage 2
            } else {
                out[idx] += 0.25f * e1v;
            }
        }
    }
}

// ===========================================================================
// Fallback (round-1 proven): atomic SpMM + f32 dense, if ws too small.
// ===========================================================================
__global__ __launch_bounds__(256) void spmm_atomic(
    const float* __restrict__ vals, const int* __restrict__ rows,
    const int* __restrict__ cols, const float* __restrict__ src_a,
    const float* __restrict__ src_b, float* __restrict__ dst)
{
    const int tid  = threadIdx.x;
    const int lane = tid & 63;
    const int e    = blockIdx.x * 4 + (tid >> 6);
    if (e >= N_EDGES) return;
    const float v = vals[e];
    const int   c = cols[e];
    const int   r = rows[e];
    const float* src = (src_b != nullptr && c >= N_USERS)
                           ? src_b + (size_t)(c - N_USERS) * EMB
                           : src_a + (size_t)c * EMB;
    unsafeAtomicAdd(&dst[(size_t)r * EMB + lane], v * src[lane]);
}

template <bool FIRST>
__global__ __launch_bounds__(256) void dense_f32(
    const float* __restrict__ t, const float* __restrict__ W,
    const float* __restrict__ user_emb, const float* __restrict__ item_emb,
    float* __restrict__ e2, float* __restrict__ out)
{
    __shared__ float wT[64][65];
    __shared__ float trow[16][64];

    const int tid = threadIdx.x;
    for (int k = tid; k < 64 * 64; k += 256) {
        const int i = k >> 6, j = k & 63;
        wT[j][i] = W[k];
    }
    const int row_base = blockIdx.x * 16;
    for (int k = tid; k < 16 * 64; k += 256) {
        const int r = k >> 6, j = k & 63;
        const int row = row_base + r;
        trow[r][j] = (row < N_NODES) ? t[(size_t)row * EMB + j] : 0.f;
    }
    __syncthreads();

    const int i  = tid & 63;
    const int r0 = tid >> 6;

    #pragma unroll
    for (int rr = 0; rr < 4; ++rr) {
        const int r   = r0 * 4 + rr;
        const int row = row_base + r;
        if (row >= N_NODES) continue;
        float acc = 0.f;
        #pragma unroll
        for (int j = 0; j < 64; ++j)
            acc = fmaf(trow[r][j], wT[j][i], acc);
        const size_t idx = (size_t)row * EMB + i;
        if (FIRST) {
            const float e1v = acc;
            const float e2v = (e1v >= 0.f) ? e1v : LEAKY * e1v;
            const float e0v = (row < N_USERS)
                                  ? user_emb[idx]
                                  : item_emb[(size_t)(row - N_USERS) * EMB + i];
            e2[idx]  = e2v;
            out[idx] = 0.25f * (e0v + e1v + e2v);
        } else {
            out[idx] += 0.25f * acc;
        }
    }
}

// ===========================================================================
extern "C" void kernel_launch(void* const* d_in, const int* in_sizes, int n_in,
                              void* d_out, int out_size, void* d_ws, size_t ws_size,
                              hipStream_t stream)
{
    const float* user_emb = (const float*)d_in[0];
    const float* item_emb = (const float*)d_in[1];
    const float* W0       = (const float*)d_in[2];
    const float* W1       = (const float*)d_in[3];
    const float* adj_vals = (const float*)d_in[4];
    const int*   adj_rows = (const int*)d_in[5];
    const int*   adj_cols = (const int*)d_in[6];
    float*       out      = (float*)d_out;

    const size_t mat_bytes = (size_t)N_NODES * EMB * sizeof(float);   // 38.4 MB
    const size_t ebf_bytes = (size_t)N_NODES * EMB * sizeof(u16);     // 19.2 MB
    const size_t edge8     = (size_t)N_EDGES * sizeof(float2);        // 19.2 MB
    const size_t hmat      = (size_t)NCH * NBKT * sizeof(int);

    // layout: [tbf 19.2 | svc transient] [sedge 19.2] [ebf 19.2] [aux] [Wbf]
    const size_t off_tbf    = 0;
    const size_t off_svc    = 0;                       // transient, inside tbf
    const size_t off_sedge  = off_tbf + ebf_bytes;
    const size_t off_ebf    = off_sedge + edge8;
    const size_t off_rowptr = off_ebf + ebf_bytes;
    const size_t off_H      = off_rowptr + (size_t)(N_NODES + 1) * sizeof(int);
    const size_t off_B      = off_H + hmat;
    const size_t off_ptr    = off_B + hmat;
    const size_t off_wbf    = (off_ptr + (size_t)(NBKT + 1) * sizeof(int) + 15) & ~(size_t)15;
    const size_t required   = off_wbf + 2 * (size_t)EMB * EMB * sizeof(u16); // ~59.5 MB

    const int spmm_blocks   = (N_NODES + 3) / 4;       // 37500
    const int densem_blocks = (NTILE + 3) / 4;         // 2344
    const int conv_blocks   = (N_NODES * EMB / 4 + 255) / 256;

    if (ws_size >= required) {
        u16*    tbf     = (u16*)((char*)d_ws + off_tbf);
        float2* svc     = (float2*)((char*)d_ws + off_svc);
        float2* sedge   = (float2*)((char*)d_ws + off_sedge);
        u16*    ebf     = (u16*)((char*)d_ws + off_ebf);
        int*    row_ptr = (int*)((char*)d_ws + off_rowptr);
        int*    H       = (int*)((char*)d_ws + off_H);
        int*    B       = (int*)((char*)d_ws + off_B);
        int*    bkt_ptr = (int*)((char*)d_ws + off_ptr);
        u16*    Wbf0    = (u16*)((char*)d_ws + off_wbf);
        u16*    Wbf1    = Wbf0 + EMB * EMB;

        // ---- bf16 sources (e0, W0, W1) ----
        conv_all<<<conv_blocks, 256, 0, stream>>>(
            user_emb, item_emb, W0, W1, ebf, Wbf0, Wbf1);

        // ---- bucket-sorted edge list + row_ptr (once, reused twice) ----
        bkt_hist<<<NCH, 1024, 0, stream>>>(adj_rows, H);
        scan_plus<<<1, 1024, 0, stream>>>(H, bkt_ptr, B);
        partition_l1<<<NCH, 1024, 0, stream>>>(
            adj_vals, adj_rows, adj_cols, B, svc);
        place_l2<<<NBKT, RB, 0, stream>>>(bkt_ptr, svc, sedge, row_ptr);
        // svc (inside tbf) is dead from here on

        // ---- stage 1: tbf = A @ e0 ; e1/e2/out ; e2 -> ebf (bf16) ----
        spmm_bf16<<<spmm_blocks, 256, 0, stream>>>(row_ptr, sedge, ebf, tbf);
        dense_mfma<true><<<densem_blocks, 256, 0, stream>>>(tbf, Wbf0, ebf, out);

        // ---- stage 2: tbf = A @ e2 ; out += 0.25*e3 ----
        spmm_bf16<<<spmm_blocks, 256, 0, stream>>>(row_ptr, sedge, ebf, tbf);
        dense_mfma<false><<<densem_blocks, 256, 0, stream>>>(tbf, Wbf1, ebf, out);
    } else {
        // ---- fallback: round-1 atomic path ----
        float* t  = (float*)d_ws;
        float* e2 = (float*)((char*)d_ws + mat_bytes);
        const int dense_blocks = (N_NODES + 15) / 16;

        hipMemsetAsync(t, 0, mat_bytes, stream);
        spmm_atomic<<<(N_EDGES + 3) / 4, 256, 0, stream>>>(
            adj_vals, adj_rows, adj_cols, user_emb, item_emb, t);
        dense_f32<true><<<dense_blocks, 256, 0, stream>>>(
            t, W0, user_emb, item_emb, e2, out);

        hipMemsetAsync(t, 0, mat_bytes, stream);
        spmm_atomic<<<(N_EDGES + 3) / 4, 256, 0, stream>>>(
            adj_vals, adj_rows, adj_cols, e2, nullptr, t);
        dense_f32<false><<<dense_blocks, 256, 0, stream>>>(
            t, W1, nullptr, nullptr, nullptr, out);
    }
}